// Round 3
// baseline (595.695 us; speedup 1.0000x reference)
//
#include <hip/hip_runtime.h>
#include <hip/hip_bf16.h>
#include <stdint.h>

// SparseMoE top-2/8, N=8192, D=1024, H=2048, fp32 in/out.
// R3: (1) GEMMs back to m97 single-buffer structure (32KB LDS) -> 4 blocks/CU
//     instead of 2 (dbuf's 64KB LDS was the occupancy cap; implicit wave-level
//     overlap replaces explicit dbuf per m99/m114);
//     (2) keep both-sides XOR swizzle (0 bank conflicts, proven R2);
//     (3) G13 fixes on all memory-bound kernels: 16B/lane stores in converts,
//     router no longer emits xb (dedicated cvt_x), combine at 16B loads.

#define N_TOK 8192
#define D_DIM 1024
#define H_DIM 2048
#define N_EXP 8
#define N_ASSIGN (N_TOK * 2)
#define BM 128
#define BN 128
#define BK 64

typedef __attribute__((ext_vector_type(8))) short short8;   // bf16x8
typedef __attribute__((ext_vector_type(4))) float f32x4;    // MFMA acc frag

__device__ __forceinline__ unsigned short f2bf(float f) {
  union { float f; unsigned int u; } v; v.f = f;
  unsigned int r = v.u + 0x7fffu + ((v.u >> 16) & 1u);  // RTNE
  return (unsigned short)(r >> 16);
}
__device__ __forceinline__ float bf2f(unsigned short u) {
  union { float f; unsigned int u; } v; v.u = ((unsigned int)u) << 16; return v.f;
}
__device__ __forceinline__ short8 pack8(float4 a, float4 b) {
  short8 o;
  o[0] = (short)f2bf(a.x); o[1] = (short)f2bf(a.y);
  o[2] = (short)f2bf(a.z); o[3] = (short)f2bf(a.w);
  o[4] = (short)f2bf(b.x); o[5] = (short)f2bf(b.y);
  o[6] = (short)f2bf(b.z); o[7] = (short)f2bf(b.w);
  return o;
}
__device__ __forceinline__ void gload_lds16(const void* g, void* l) {
  __builtin_amdgcn_global_load_lds((const __attribute__((address_space(1))) void*)g,
                                   (__attribute__((address_space(3))) void*)l, 16, 0, 0);
}

// ---------------- tiny setup kernels ----------------
__global__ void zero_cnt_kernel(int* cnt) {
  if (threadIdx.x < N_EXP) cnt[threadIdx.x] = 0;
}

// fp32 -> bf16, 8 elems/thread (16B stores)
__global__ void cvt_x_kernel(const float* __restrict__ src,
                             unsigned short* __restrict__ dst) {
  size_t i = ((size_t)blockIdx.x * 256 + threadIdx.x) * 8;
  float4 a = *(const float4*)(src + i);
  float4 b = *(const float4*)(src + i + 4);
  *(short8*)(dst + i) = pack8(a, b);
}

// gate/up -> interleaved wgu [E][4096][D]: 16-row group 2g = gate, 2g+1 = up
__global__ void cvt_gu_kernel(const float* __restrict__ g, const float* __restrict__ u,
                              unsigned short* __restrict__ dst) {
  int up = blockIdx.y;
  const float* src = up ? u : g;
  size_t i = ((size_t)blockIdx.x * 256 + threadIdx.x) * 8;
  float4 a = *(const float4*)(src + i);
  float4 b = *(const float4*)(src + i + 4);
  int j = (int)(i >> 10);              // source row = e*H + jj
  int e = j >> 11;
  int jj = j & (H_DIM - 1);
  int n = ((jj >> 4) << 5) + (up ? 16 : 0) + (jj & 15);
  size_t di = (((size_t)(e << 12) + n) << 10) + (i & 1023);
  *(short8*)(dst + di) = pack8(a, b);
}

// ---------------- router: fp32 logits, softmax, top-2, slot assignment ------
__global__ __launch_bounds__(256) void router_kernel(
    const float* __restrict__ x, const float* __restrict__ rw,
    const float* __restrict__ rb,
    int4* __restrict__ tiidx,                 // (e1,e2,slot1,slot2)
    float2* __restrict__ tiw,                 // (w1,w2) normalized
    int* __restrict__ cnt) {
  __shared__ float sw[N_EXP][D_DIM];          // 32 KB router weights
  int tid = threadIdx.x;
  for (int i = tid * 4; i < N_EXP * D_DIM; i += 256 * 4)
    *(float4*)&sw[0][i] = *(const float4*)(rw + i);
  __syncthreads();

  int wave = tid >> 6, lane = tid & 63;
  int t = blockIdx.x * 4 + wave;
  const float* xr = x + (size_t)t * D_DIM;
  float xs[16];
#pragma unroll
  for (int j = 0; j < 16; j++) xs[j] = xr[lane + 64 * j];

  float logit[N_EXP];
#pragma unroll
  for (int e = 0; e < N_EXP; e++) {
    float acc = 0.f;
#pragma unroll
    for (int j = 0; j < 16; j++) acc += xs[j] * sw[e][lane + 64 * j];
#pragma unroll
    for (int off = 32; off; off >>= 1) acc += __shfl_xor(acc, off);
    logit[e] = acc + rb[e];
  }
  if (lane == 0) {
    float m = logit[0];
#pragma unroll
    for (int e = 1; e < N_EXP; e++) m = fmaxf(m, logit[e]);
    float p[N_EXP], S = 0.f;
#pragma unroll
    for (int e = 0; e < N_EXP; e++) { p[e] = expf(logit[e] - m); S += p[e]; }
#pragma unroll
    for (int e = 0; e < N_EXP; e++) p[e] /= S;
    int i1 = 0; float v1 = p[0];
#pragma unroll
    for (int e = 1; e < N_EXP; e++) if (p[e] > v1) { v1 = p[e]; i1 = e; }
    int i2 = -1; float v2 = -1.f;
#pragma unroll
    for (int e = 0; e < N_EXP; e++) if (e != i1 && p[e] > v2) { v2 = p[e]; i2 = e; }
    float inv = 1.f / (v1 + v2 + 1e-9f);
    int s1 = atomicAdd(&cnt[i1], 1);
    int s2 = atomicAdd(&cnt[i2], 1);
    tiidx[t] = make_int4(i1, i2, s1, s2);
    tiw[t] = make_float2(v1 * inv, v2 * inv);
  }
}

__global__ void offsets_kernel(const int* __restrict__ cnt, int* __restrict__ off) {
  if (threadIdx.x == 0) {
    int a = 0;
    for (int e = 0; e < N_EXP; e++) { off[e] = a; a += cnt[e]; }
    off[N_EXP] = a;
  }
}

__global__ void scatter_kernel(const int4* __restrict__ tiidx,
                               const int* __restrict__ off,
                               int* __restrict__ assign, int2* __restrict__ trows) {
  int t = blockIdx.x * 256 + threadIdx.x;
  if (t >= N_TOK) return;
  int4 ti = tiidx[t];
  int r1 = off[ti.x] + ti.z;
  int r2 = off[ti.y] + ti.w;
  assign[r1] = t;
  assign[r2] = t;
  trows[t] = make_int2(r1, r2);
}

// ---------------- GEMM1: fused gate+up over interleaved wgu ----------------
__global__ __launch_bounds__(256) void gemm_gateup(
    const unsigned short* __restrict__ xb,    // [N_TOK, D] bf16
    const unsigned short* __restrict__ wgu,   // [E*4096, D] bf16 interleaved
    const int* __restrict__ cnt, const int* __restrict__ off,
    const int* __restrict__ assign,
    unsigned short* __restrict__ hbuf) {      // [N_ASSIGN, H] bf16
  int e = blockIdx.z;
  int nrows = cnt[e];
  int row0 = blockIdx.y * BM;
  if (row0 >= nrows) return;
  int col0 = blockIdx.x * BN;                 // in [0, 4096)
  int base = off[e];

  __shared__ unsigned short sA[BM][BK];       // 16 KB
  __shared__ unsigned short sB[BN][BK];       // 16 KB

  int tid = threadIdx.x;
  int srow = tid >> 3;                        // 0..31
  int dst8 = (tid & 7) * 8;                   // linear LDS chunk
  int src8 = ((tid & 7) ^ (srow & 7)) * 8;    // pre-swizzled global column

  const unsigned short* asrc[4];
  const unsigned short* bsrc[4];
#pragma unroll
  for (int i = 0; i < 4; i++) {
    int r = row0 + srow + 32 * i;
    int tok = (r < nrows) ? assign[base + r] : assign[base];
    asrc[i] = xb + (size_t)tok * D_DIM + src8;
    int wrow = (e << 12) + col0 + srow + 32 * i;
    bsrc[i] = wgu + (size_t)wrow * D_DIM + src8;
  }

  int wr = (tid >> 7) & 1, wc = (tid >> 6) & 1;
  int lane = tid & 63;
  int fr = lane & 15;
  int fk = (lane >> 4) * 8;
  int rx = (fr & 7) * 8;                      // read-side swizzle XOR

  f32x4 acc[4][4];
#pragma unroll
  for (int a = 0; a < 4; a++)
#pragma unroll
    for (int b = 0; b < 4; b++) acc[a][b] = (f32x4){0.f, 0.f, 0.f, 0.f};

  for (int k0 = 0; k0 < D_DIM; k0 += BK) {
#pragma unroll
    for (int i = 0; i < 4; i++) {
      gload_lds16(asrc[i] + k0, &sA[srow + 32 * i][dst8]);
      gload_lds16(bsrc[i] + k0, &sB[srow + 32 * i][dst8]);
    }
    __syncthreads();
#pragma unroll
    for (int ks = 0; ks < 2; ks++) {
      short8 af[4], bq[4];
      int c = (ks * 32 + fk) ^ rx;
#pragma unroll
      for (int mb = 0; mb < 4; mb++)
        af[mb] = *(const short8*)&sA[wr * 64 + mb * 16 + fr][c];
#pragma unroll
      for (int nb = 0; nb < 4; nb++)
        bq[nb] = *(const short8*)&sB[wc * 64 + nb * 16 + fr][c];
#pragma unroll
      for (int mb = 0; mb < 4; mb++)
#pragma unroll
        for (int nb = 0; nb < 4; nb++)
          acc[mb][nb] = __builtin_amdgcn_mfma_f32_16x16x32_bf16(
              af[mb], bq[nb], acc[mb][nb], 0, 0, 0);
    }
    __syncthreads();
  }

  int rowlim = nrows - row0;
#pragma unroll
  for (int mb = 0; mb < 4; mb++)
#pragma unroll
    for (int r = 0; r < 4; r++) {
      int lrow = wr * 64 + mb * 16 + (lane >> 4) * 4 + r;
      if (lrow < rowlim) {
        size_t hrow = (size_t)(base + row0 + lrow);
#pragma unroll
        for (int nbp = 0; nbp < 2; nbp++) {
          float g = acc[mb][2 * nbp][r], u = acc[mb][2 * nbp + 1][r];
          float hv = g / (1.f + __expf(-g)) * u;     // silu(g)*u
          int hcol = (col0 >> 1) + wc * 32 + nbp * 16 + (lane & 15);
          hbuf[hrow * H_DIM + hcol] = f2bf(hv);
        }
      }
    }
}

// ---------------- GEMM2: e_out = h @ Wd^T -----------------------------------
__global__ __launch_bounds__(256) void gemm_down(
    const unsigned short* __restrict__ hbuf,  // [N_ASSIGN, H] bf16
    const unsigned short* __restrict__ wd,    // [E*D, H] bf16
    const int* __restrict__ cnt, const int* __restrict__ off,
    unsigned short* __restrict__ eo) {        // [N_ASSIGN, D] bf16
  int e = blockIdx.z;
  int nrows = cnt[e];
  int row0 = blockIdx.y * BM;
  if (row0 >= nrows) return;
  int col0 = blockIdx.x * BN;
  int base = off[e];

  __shared__ unsigned short sA[BM][BK];
  __shared__ unsigned short sB[BN][BK];

  int tid = threadIdx.x;
  int srow = tid >> 3;
  int dst8 = (tid & 7) * 8;
  int src8 = ((tid & 7) ^ (srow & 7)) * 8;

  const unsigned short* asrc[4];
  const unsigned short* bsrc[4];
#pragma unroll
  for (int i = 0; i < 4; i++) {
    int r = row0 + srow + 32 * i;
    int hrow = base + ((r < nrows) ? r : 0);
    asrc[i] = hbuf + (size_t)hrow * H_DIM + src8;
    int wrow = e * D_DIM + col0 + srow + 32 * i;
    bsrc[i] = wd + (size_t)wrow * H_DIM + src8;
  }

  int wr = (tid >> 7) & 1, wc = (tid >> 6) & 1;
  int lane = tid & 63;
  int fr = lane & 15;
  int fk = (lane >> 4) * 8;
  int rx = (fr & 7) * 8;

  f32x4 acc[4][4];
#pragma unroll
  for (int a = 0; a < 4; a++)
#pragma unroll
    for (int b = 0; b < 4; b++) acc[a][b] = (f32x4){0.f, 0.f, 0.f, 0.f};

  for (int k0 = 0; k0 < H_DIM; k0 += BK) {
#pragma unroll
    for (int i = 0; i < 4; i++) {
      gload_lds16(asrc[i] + k0, &sA[srow + 32 * i][dst8]);
      gload_lds16(bsrc[i] + k0, &sB[srow + 32 * i][dst8]);
    }
    __syncthreads();
#pragma unroll
    for (int ks = 0; ks < 2; ks++) {
      short8 af[4], bq[4];
      int c = (ks * 32 + fk) ^ rx;
#pragma unroll
      for (int mb = 0; mb < 4; mb++)
        af[mb] = *(const short8*)&sA[wr * 64 + mb * 16 + fr][c];
#pragma unroll
      for (int nb = 0; nb < 4; nb++)
        bq[nb] = *(const short8*)&sB[wc * 64 + nb * 16 + fr][c];
#pragma unroll
      for (int mb = 0; mb < 4; mb++)
#pragma unroll
        for (int nb = 0; nb < 4; nb++)
          acc[mb][nb] = __builtin_amdgcn_mfma_f32_16x16x32_bf16(
              af[mb], bq[nb], acc[mb][nb], 0, 0, 0);
    }
    __syncthreads();
  }

  int rowlim = nrows - row0;
#pragma unroll
  for (int mb = 0; mb < 4; mb++)
#pragma unroll
    for (int r = 0; r < 4; r++) {
      int lrow = wr * 64 + mb * 16 + (lane >> 4) * 4 + r;
      if (lrow < rowlim) {
        size_t orow = (size_t)(base + row0 + lrow);
#pragma unroll
        for (int nb = 0; nb < 4; nb++)
          eo[orow * D_DIM + col0 + wc * 64 + nb * 16 + (lane & 15)] = f2bf(acc[mb][nb][r]);
      }
    }
}

// ---------------- combine: out[t] = w1*eo[r1] + w2*eo[r2] -------------------
__global__ __launch_bounds__(256) void combine_kernel(
    const unsigned short* __restrict__ eo, const int2* __restrict__ trows,
    const float2* __restrict__ tiw, float* __restrict__ out) {
  int t = blockIdx.x * 2 + (threadIdx.x >> 7);
  int l = threadIdx.x & 127;
  int c = l * 8;
  int2 r = trows[t];
  float2 w = tiw[t];
  short8 a = *(const short8*)&eo[(size_t)r.x * D_DIM + c];
  short8 b = *(const short8*)&eo[(size_t)r.y * D_DIM + c];
  float4 o0, o1;
  o0.x = w.x * bf2f((unsigned short)a[0]) + w.y * bf2f((unsigned short)b[0]);
  o0.y = w.x * bf2f((unsigned short)a[1]) + w.y * bf2f((unsigned short)b[1]);
  o0.z = w.x * bf2f((unsigned short)a[2]) + w.y * bf2f((unsigned short)b[2]);
  o0.w = w.x * bf2f((unsigned short)a[3]) + w.y * bf2f((unsigned short)b[3]);
  o1.x = w.x * bf2f((unsigned short)a[4]) + w.y * bf2f((unsigned short)b[4]);
  o1.y = w.x * bf2f((unsigned short)a[5]) + w.y * bf2f((unsigned short)b[5]);
  o1.z = w.x * bf2f((unsigned short)a[6]) + w.y * bf2f((unsigned short)b[6]);
  o1.w = w.x * bf2f((unsigned short)a[7]) + w.y * bf2f((unsigned short)b[7]);
  *(float4*)&out[(size_t)t * D_DIM + c] = o0;
  *(float4*)&out[(size_t)t * D_DIM + c + 4] = o1;
}

extern "C" void kernel_launch(void* const* d_in, const int* in_sizes, int n_in,
                              void* d_out, int out_size, void* d_ws, size_t ws_size,
                              hipStream_t stream) {
  const float* x  = (const float*)d_in[0];
  const float* rw = (const float*)d_in[1];
  const float* rb = (const float*)d_in[2];
  const float* wg = (const float*)d_in[3];
  const float* wu = (const float*)d_in[4];
  const float* wd = (const float*)d_in[5];
  float* out = (float*)d_out;

  char* ws = (char*)d_ws;
  size_t o = 0;
  auto alloc = [&](size_t b) { char* p = ws + o; o += (b + 255) & ~(size_t)255; return p; };
  unsigned short* xb  = (unsigned short*)alloc((size_t)N_TOK * D_DIM * 2);           // 16.8 MB
  unsigned short* wgu = (unsigned short*)alloc((size_t)N_EXP * 4096 * D_DIM * 2);    // 67.1 MB
  unsigned short* wdb = (unsigned short*)alloc((size_t)N_EXP * D_DIM * H_DIM * 2);   // 33.6 MB
  unsigned short* hb  = (unsigned short*)alloc((size_t)N_ASSIGN * H_DIM * 2);        // 67.1 MB
  unsigned short* eob = (unsigned short*)alloc((size_t)N_ASSIGN * D_DIM * 2);        // 33.6 MB
  int*    assign = (int*)alloc(N_ASSIGN * 4);
  int4*   tiidx  = (int4*)alloc(N_TOK * 16);
  float2* tiw    = (float2*)alloc(N_TOK * 8);
  int2*   trows  = (int2*)alloc(N_TOK * 8);
  int*    cnt    = (int*)alloc(64);
  int*    off    = (int*)alloc(64);

  const int wElems = N_EXP * H_DIM * D_DIM;  // 16,777,216

  zero_cnt_kernel<<<1, 64, 0, stream>>>(cnt);
  cvt_x_kernel<<<(N_TOK * D_DIM) / 2048, 256, 0, stream>>>(x, xb);
  cvt_gu_kernel<<<dim3(wElems / 2048, 2), 256, 0, stream>>>(wg, wu, wgu);
  cvt_x_kernel<<<wElems / 2048, 256, 0, stream>>>(wd, wdb);
  router_kernel<<<N_TOK / 4, 256, 0, stream>>>(x, rw, rb, tiidx, tiw, cnt);
  offsets_kernel<<<1, 1, 0, stream>>>(cnt, off);
  scatter_kernel<<<N_TOK / 256, 256, 0, stream>>>(tiidx, off, assign, trows);
  gemm_gateup<<<dim3(4096 / BN, N_TOK / BM, N_EXP), 256, 0, stream>>>(
      xb, wgu, cnt, off, assign, hb);
  gemm_down<<<dim3(D_DIM / BN, N_TOK / BM, N_EXP), 256, 0, stream>>>(
      hb, wdb, cnt, off, eob);
  combine_kernel<<<N_TOK / 2, 256, 0, stream>>>(eob, trows, tiw, out);
}

// Round 4
// 555.450 us; speedup vs baseline: 1.0725x; 1.0725x over previous
//
#include <hip/hip_runtime.h>
#include <hip/hip_bf16.h>
#include <stdint.h>

// SparseMoE top-2/8, N=8192, D=1024, H=2048, fp32 in/out.
// R4: (1) GEMMs reverted to R2's proven dbuf 2-phase + both-sides XOR swizzle
//     (648 TF; R3's single-buffer regressed -- occupancy was NOT LDS-capped);
//     (2) launch fusion 10->6: prep(all converts+cnt zero), router(+bf16 x
//     emit via packed uint stores), plan(offsets+scatter single block);
//     (3) 8-phase 256^2 schedule staged for next round (sync-structure risk).

#define N_TOK 8192
#define D_DIM 1024
#define H_DIM 2048
#define N_EXP 8
#define N_ASSIGN (N_TOK * 2)
#define BM 128
#define BN 128
#define BK 64

typedef __attribute__((ext_vector_type(8))) short short8;   // bf16x8
typedef __attribute__((ext_vector_type(4))) float f32x4;    // MFMA acc frag

__device__ __forceinline__ unsigned short f2bf(float f) {
  union { float f; unsigned int u; } v; v.f = f;
  unsigned int r = v.u + 0x7fffu + ((v.u >> 16) & 1u);  // RTNE
  return (unsigned short)(r >> 16);
}
__device__ __forceinline__ float bf2f(unsigned short u) {
  union { float f; unsigned int u; } v; v.u = ((unsigned int)u) << 16; return v.f;
}
__device__ __forceinline__ short8 pack8(float4 a, float4 b) {
  short8 o;
  o[0] = (short)f2bf(a.x); o[1] = (short)f2bf(a.y);
  o[2] = (short)f2bf(a.z); o[3] = (short)f2bf(a.w);
  o[4] = (short)f2bf(b.x); o[5] = (short)f2bf(b.y);
  o[6] = (short)f2bf(b.z); o[7] = (short)f2bf(b.w);
  return o;
}
__device__ __forceinline__ void gload_lds16(const void* g, void* l) {
  __builtin_amdgcn_global_load_lds((const __attribute__((address_space(1))) void*)g,
                                   (__attribute__((address_space(3))) void*)l, 16, 0, 0);
}

// ---------------- prep: all weight converts + cnt zeroing -------------------
// blocks [0,16384): gate/up -> interleaved wgu [E][4096][D]
//        [16384,24576): wd -> bf16
__global__ __launch_bounds__(256) void prep_kernel(
    const float* __restrict__ wg, const float* __restrict__ wu,
    const float* __restrict__ wd,
    unsigned short* __restrict__ wgu, unsigned short* __restrict__ wdb,
    int* __restrict__ cnt) {
  int b = blockIdx.x;
  if (b == 0 && threadIdx.x < 16) cnt[threadIdx.x] = 0;
  if (b < 16384) {
    int up = b >> 13;                        // 0 = gate, 1 = up
    size_t i = (((size_t)(b & 8191)) * 256 + threadIdx.x) * 8;
    const float* src = up ? wu : wg;
    float4 a = *(const float4*)(src + i);
    float4 c = *(const float4*)(src + i + 4);
    int j = (int)(i >> 10);                  // source row = e*H + jj
    int e = j >> 11;
    int jj = j & (H_DIM - 1);
    int n = ((jj >> 4) << 5) + (up ? 16 : 0) + (jj & 15);
    size_t di = (((size_t)(e << 12) + n) << 10) + (i & 1023);
    *(short8*)(wgu + di) = pack8(a, c);
  } else {
    size_t i = (((size_t)(b - 16384)) * 256 + threadIdx.x) * 8;
    float4 a = *(const float4*)(wd + i);
    float4 c = *(const float4*)(wd + i + 4);
    *(short8*)(wdb + i) = pack8(a, c);
  }
}

// ---------------- router: fp32 logits + top-2 + bf16 x emit -----------------
__global__ __launch_bounds__(256) void router_kernel(
    const float* __restrict__ x, const float* __restrict__ rw,
    const float* __restrict__ rb,
    unsigned short* __restrict__ xb,
    int4* __restrict__ tiidx, float2* __restrict__ tiw, int* __restrict__ cnt) {
  __shared__ float sw[N_EXP][D_DIM];          // 32 KB router weights
  int tid = threadIdx.x;
  for (int i = tid * 4; i < N_EXP * D_DIM; i += 1024)
    *(float4*)&sw[0][i] = *(const float4*)(rw + i);
  __syncthreads();

  int wave = tid >> 6, lane = tid & 63;
  int t = blockIdx.x * 4 + wave;
  const float2* xr = (const float2*)(x + (size_t)t * D_DIM);
  float2 xs[8];
#pragma unroll
  for (int j = 0; j < 8; j++) xs[j] = xr[lane + 64 * j];
  // emit bf16 x, 4B packed per lane (coalesced)
  unsigned int* xbo = (unsigned int*)(xb + (size_t)t * D_DIM);
#pragma unroll
  for (int j = 0; j < 8; j++) {
    unsigned int pk = ((unsigned int)f2bf(xs[j].y) << 16) | (unsigned int)f2bf(xs[j].x);
    xbo[lane + 64 * j] = pk;
  }

  float logit[N_EXP];
#pragma unroll
  for (int e = 0; e < N_EXP; e++) {
    float acc = 0.f;
    const float2* swe = (const float2*)sw[e];
#pragma unroll
    for (int j = 0; j < 8; j++) {
      float2 w2 = swe[lane + 64 * j];
      acc += xs[j].x * w2.x + xs[j].y * w2.y;
    }
#pragma unroll
    for (int off = 32; off; off >>= 1) acc += __shfl_xor(acc, off);
    logit[e] = acc + rb[e];
  }
  if (lane == 0) {
    float m = logit[0];
#pragma unroll
    for (int e = 1; e < N_EXP; e++) m = fmaxf(m, logit[e]);
    float p[N_EXP], S = 0.f;
#pragma unroll
    for (int e = 0; e < N_EXP; e++) { p[e] = expf(logit[e] - m); S += p[e]; }
#pragma unroll
    for (int e = 0; e < N_EXP; e++) p[e] /= S;
    int i1 = 0; float v1 = p[0];
#pragma unroll
    for (int e = 1; e < N_EXP; e++) if (p[e] > v1) { v1 = p[e]; i1 = e; }
    int i2 = -1; float v2 = -1.f;
#pragma unroll
    for (int e = 0; e < N_EXP; e++) if (e != i1 && p[e] > v2) { v2 = p[e]; i2 = e; }
    float inv = 1.f / (v1 + v2 + 1e-9f);
    int s1 = atomicAdd(&cnt[i1], 1);
    int s2 = atomicAdd(&cnt[i2], 1);
    tiidx[t] = make_int4(i1, i2, s1, s2);
    tiw[t] = make_float2(v1 * inv, v2 * inv);
  }
}

// ---------------- plan: offsets + scatter, one block ------------------------
__global__ __launch_bounds__(256) void plan_kernel(
    const int4* __restrict__ tiidx, const int* __restrict__ cnt,
    int* __restrict__ off, int* __restrict__ assign, int2* __restrict__ trows) {
  __shared__ int soff[N_EXP];
  if (threadIdx.x == 0) {
    int a = 0;
    for (int e = 0; e < N_EXP; e++) { soff[e] = a; off[e] = a; a += cnt[e]; }
    off[N_EXP] = a;
  }
  __syncthreads();
  for (int t = threadIdx.x; t < N_TOK; t += 256) {
    int4 ti = tiidx[t];
    int r1 = soff[ti.x] + ti.z;
    int r2 = soff[ti.y] + ti.w;
    assign[r1] = t;
    assign[r2] = t;
    trows[t] = make_int2(r1, r2);
  }
}

// ---------------- GEMM1: fused gate+up over interleaved wgu ----------------
__global__ __launch_bounds__(256) void gemm_gateup(
    const unsigned short* __restrict__ xb,    // [N_TOK, D] bf16
    const unsigned short* __restrict__ wgu,   // [E*4096, D] bf16 interleaved
    const int* __restrict__ cnt, const int* __restrict__ off,
    const int* __restrict__ assign,
    unsigned short* __restrict__ hbuf) {      // [N_ASSIGN, H] bf16
  int e = blockIdx.z;
  int nrows = cnt[e];
  int row0 = blockIdx.y * BM;
  if (row0 >= nrows) return;
  int col0 = blockIdx.x * BN;                 // in [0, 4096)
  int base = off[e];

  __shared__ unsigned short sA[2][BM][BK];
  __shared__ unsigned short sB[2][BN][BK];

  int tid = threadIdx.x;
  int srow = tid >> 3;                        // 0..31
  int dst8 = (tid & 7) * 8;                   // linear LDS chunk
  int src8 = ((tid & 7) ^ (srow & 7)) * 8;    // pre-swizzled global column

  const unsigned short* asrc[4];
  const unsigned short* bsrc[4];
#pragma unroll
  for (int i = 0; i < 4; i++) {
    int r = row0 + srow + 32 * i;
    int tok = (r < nrows) ? assign[base + r] : assign[base];
    asrc[i] = xb + (size_t)tok * D_DIM + src8;
    int wrow = (e << 12) + col0 + srow + 32 * i;
    bsrc[i] = wgu + (size_t)wrow * D_DIM + src8;
  }

  int wr = (tid >> 7) & 1, wc = (tid >> 6) & 1;
  int lane = tid & 63;
  int fr = lane & 15;
  int fk = (lane >> 4) * 8;
  int rx = (fr & 7) * 8;                      // read-side swizzle XOR

  f32x4 acc[4][4];
#pragma unroll
  for (int a = 0; a < 4; a++)
#pragma unroll
    for (int b = 0; b < 4; b++) acc[a][b] = (f32x4){0.f, 0.f, 0.f, 0.f};

#define STAGE(bf, k0)                                                       \
  _Pragma("unroll")                                                         \
  for (int i = 0; i < 4; i++) {                                             \
    gload_lds16(asrc[i] + (k0), &sA[bf][srow + 32 * i][dst8]);              \
    gload_lds16(bsrc[i] + (k0), &sB[bf][srow + 32 * i][dst8]);              \
  }
#define COMPUTE(bf)                                                         \
  _Pragma("unroll")                                                         \
  for (int ks = 0; ks < 2; ks++) {                                          \
    short8 af[4], bq[4];                                                    \
    int c = (ks * 32 + fk) ^ rx;                                            \
    _Pragma("unroll")                                                       \
    for (int mb = 0; mb < 4; mb++)                                          \
      af[mb] = *(const short8*)&sA[bf][wr * 64 + mb * 16 + fr][c];          \
    _Pragma("unroll")                                                       \
    for (int nb = 0; nb < 4; nb++)                                          \
      bq[nb] = *(const short8*)&sB[bf][wc * 64 + nb * 16 + fr][c];          \
    _Pragma("unroll")                                                       \
    for (int mb = 0; mb < 4; mb++)                                          \
      _Pragma("unroll")                                                     \
      for (int nb = 0; nb < 4; nb++)                                        \
        acc[mb][nb] = __builtin_amdgcn_mfma_f32_16x16x32_bf16(              \
            af[mb], bq[nb], acc[mb][nb], 0, 0, 0);                          \
  }

  STAGE(0, 0);
  __syncthreads();
  for (int k0 = 0; k0 < D_DIM - 128; k0 += 128) {
    STAGE(1, k0 + 64);  COMPUTE(0); __syncthreads();
    STAGE(0, k0 + 128); COMPUTE(1); __syncthreads();
  }
  STAGE(1, D_DIM - 64); COMPUTE(0); __syncthreads();
  COMPUTE(1);
#undef STAGE
#undef COMPUTE

  int rowlim = nrows - row0;
#pragma unroll
  for (int mb = 0; mb < 4; mb++)
#pragma unroll
    for (int r = 0; r < 4; r++) {
      int lrow = wr * 64 + mb * 16 + (lane >> 4) * 4 + r;
      if (lrow < rowlim) {
        size_t hrow = (size_t)(base + row0 + lrow);
#pragma unroll
        for (int nbp = 0; nbp < 2; nbp++) {
          float g = acc[mb][2 * nbp][r], u = acc[mb][2 * nbp + 1][r];
          float hv = g / (1.f + __expf(-g)) * u;     // silu(g)*u
          int hcol = (col0 >> 1) + wc * 32 + nbp * 16 + (lane & 15);
          hbuf[hrow * H_DIM + hcol] = f2bf(hv);
        }
      }
    }
}

// ---------------- GEMM2: e_out = h @ Wd^T -----------------------------------
__global__ __launch_bounds__(256) void gemm_down(
    const unsigned short* __restrict__ hbuf,  // [N_ASSIGN, H] bf16
    const unsigned short* __restrict__ wd,    // [E*D, H] bf16
    const int* __restrict__ cnt, const int* __restrict__ off,
    unsigned short* __restrict__ eo) {        // [N_ASSIGN, D] bf16
  int e = blockIdx.z;
  int nrows = cnt[e];
  int row0 = blockIdx.y * BM;
  if (row0 >= nrows) return;
  int col0 = blockIdx.x * BN;
  int base = off[e];

  __shared__ unsigned short sA[2][BM][BK];
  __shared__ unsigned short sB[2][BN][BK];

  int tid = threadIdx.x;
  int srow = tid >> 3;
  int dst8 = (tid & 7) * 8;
  int src8 = ((tid & 7) ^ (srow & 7)) * 8;

  const unsigned short* asrc[4];
  const unsigned short* bsrc[4];
#pragma unroll
  for (int i = 0; i < 4; i++) {
    int r = row0 + srow + 32 * i;
    int hrow = base + ((r < nrows) ? r : 0);
    asrc[i] = hbuf + (size_t)hrow * H_DIM + src8;
    int wrow = e * D_DIM + col0 + srow + 32 * i;
    bsrc[i] = wd + (size_t)wrow * H_DIM + src8;
  }

  int wr = (tid >> 7) & 1, wc = (tid >> 6) & 1;
  int lane = tid & 63;
  int fr = lane & 15;
  int fk = (lane >> 4) * 8;
  int rx = (fr & 7) * 8;

  f32x4 acc[4][4];
#pragma unroll
  for (int a = 0; a < 4; a++)
#pragma unroll
    for (int b = 0; b < 4; b++) acc[a][b] = (f32x4){0.f, 0.f, 0.f, 0.f};

#define STAGE(bf, k0)                                                       \
  _Pragma("unroll")                                                         \
  for (int i = 0; i < 4; i++) {                                             \
    gload_lds16(asrc[i] + (k0), &sA[bf][srow + 32 * i][dst8]);              \
    gload_lds16(bsrc[i] + (k0), &sB[bf][srow + 32 * i][dst8]);              \
  }
#define COMPUTE(bf)                                                         \
  _Pragma("unroll")                                                         \
  for (int ks = 0; ks < 2; ks++) {                                          \
    short8 af[4], bq[4];                                                    \
    int c = (ks * 32 + fk) ^ rx;                                            \
    _Pragma("unroll")                                                       \
    for (int mb = 0; mb < 4; mb++)                                          \
      af[mb] = *(const short8*)&sA[bf][wr * 64 + mb * 16 + fr][c];          \
    _Pragma("unroll")                                                       \
    for (int nb = 0; nb < 4; nb++)                                          \
      bq[nb] = *(const short8*)&sB[bf][wc * 64 + nb * 16 + fr][c];          \
    _Pragma("unroll")                                                       \
    for (int mb = 0; mb < 4; mb++)                                          \
      _Pragma("unroll")                                                     \
      for (int nb = 0; nb < 4; nb++)                                        \
        acc[mb][nb] = __builtin_amdgcn_mfma_f32_16x16x32_bf16(              \
            af[mb], bq[nb], acc[mb][nb], 0, 0, 0);                          \
  }

  STAGE(0, 0);
  __syncthreads();
  for (int k0 = 0; k0 < H_DIM - 128; k0 += 128) {
    STAGE(1, k0 + 64);  COMPUTE(0); __syncthreads();
    STAGE(0, k0 + 128); COMPUTE(1); __syncthreads();
  }
  STAGE(1, H_DIM - 64); COMPUTE(0); __syncthreads();
  COMPUTE(1);
#undef STAGE
#undef COMPUTE

  int rowlim = nrows - row0;
#pragma unroll
  for (int mb = 0; mb < 4; mb++)
#pragma unroll
    for (int r = 0; r < 4; r++) {
      int lrow = wr * 64 + mb * 16 + (lane >> 4) * 4 + r;
      if (lrow < rowlim) {
        size_t orow = (size_t)(base + row0 + lrow);
#pragma unroll
        for (int nb = 0; nb < 4; nb++)
          eo[orow * D_DIM + col0 + wc * 64 + nb * 16 + (lane & 15)] = f2bf(acc[mb][nb][r]);
      }
    }
}

// ---------------- combine: out[t] = w1*eo[r1] + w2*eo[r2] -------------------
__global__ __launch_bounds__(256) void combine_kernel(
    const unsigned short* __restrict__ eo, const int2* __restrict__ trows,
    const float2* __restrict__ tiw, float* __restrict__ out) {
  int t = blockIdx.x * 2 + (threadIdx.x >> 7);
  int l = threadIdx.x & 127;
  int c = l * 8;
  int2 r = trows[t];
  float2 w = tiw[t];
  short8 a = *(const short8*)&eo[(size_t)r.x * D_DIM + c];
  short8 b = *(const short8*)&eo[(size_t)r.y * D_DIM + c];
  float4 o0, o1;
  o0.x = w.x * bf2f((unsigned short)a[0]) + w.y * bf2f((unsigned short)b[0]);
  o0.y = w.x * bf2f((unsigned short)a[1]) + w.y * bf2f((unsigned short)b[1]);
  o0.z = w.x * bf2f((unsigned short)a[2]) + w.y * bf2f((unsigned short)b[2]);
  o0.w = w.x * bf2f((unsigned short)a[3]) + w.y * bf2f((unsigned short)b[3]);
  o1.x = w.x * bf2f((unsigned short)a[4]) + w.y * bf2f((unsigned short)b[4]);
  o1.y = w.x * bf2f((unsigned short)a[5]) + w.y * bf2f((unsigned short)b[5]);
  o1.z = w.x * bf2f((unsigned short)a[6]) + w.y * bf2f((unsigned short)b[6]);
  o1.w = w.x * bf2f((unsigned short)a[7]) + w.y * bf2f((unsigned short)b[7]);
  *(float4*)&out[(size_t)t * D_DIM + c] = o0;
  *(float4*)&out[(size_t)t * D_DIM + c + 4] = o1;
}

extern "C" void kernel_launch(void* const* d_in, const int* in_sizes, int n_in,
                              void* d_out, int out_size, void* d_ws, size_t ws_size,
                              hipStream_t stream) {
  const float* x  = (const float*)d_in[0];
  const float* rw = (const float*)d_in[1];
  const float* rb = (const float*)d_in[2];
  const float* wg = (const float*)d_in[3];
  const float* wu = (const float*)d_in[4];
  const float* wd = (const float*)d_in[5];
  float* out = (float*)d_out;

  char* ws = (char*)d_ws;
  size_t o = 0;
  auto alloc = [&](size_t b) { char* p = ws + o; o += (b + 255) & ~(size_t)255; return p; };
  unsigned short* xb  = (unsigned short*)alloc((size_t)N_TOK * D_DIM * 2);           // 16.8 MB
  unsigned short* wgu = (unsigned short*)alloc((size_t)N_EXP * 4096 * D_DIM * 2);    // 67.1 MB
  unsigned short* wdb = (unsigned short*)alloc((size_t)N_EXP * D_DIM * H_DIM * 2);   // 33.6 MB
  unsigned short* hb  = (unsigned short*)alloc((size_t)N_ASSIGN * H_DIM * 2);        // 67.1 MB
  unsigned short* eob = (unsigned short*)alloc((size_t)N_ASSIGN * D_DIM * 2);        // 33.6 MB
  int*    assign = (int*)alloc(N_ASSIGN * 4);
  int4*   tiidx  = (int4*)alloc(N_TOK * 16);
  float2* tiw    = (float2*)alloc(N_TOK * 8);
  int2*   trows  = (int2*)alloc(N_TOK * 8);
  int*    cnt    = (int*)alloc(64);
  int*    off    = (int*)alloc(64);

  prep_kernel<<<24576, 256, 0, stream>>>(wg, wu, wd, wgu, wdb, cnt);
  router_kernel<<<N_TOK / 4, 256, 0, stream>>>(x, rw, rb, xb, tiidx, tiw, cnt);
  plan_kernel<<<1, 256, 0, stream>>>(tiidx, cnt, off, assign, trows);
  gemm_gateup<<<dim3(4096 / BN, N_TOK / BM, N_EXP), 256, 0, stream>>>(
      xb, wgu, cnt, off, assign, hb);
  gemm_down<<<dim3(D_DIM / BN, N_TOK / BM, N_EXP), 256, 0, stream>>>(
      hb, wdb, cnt, off, eob);
  combine_kernel<<<N_TOK / 2, 256, 0, stream>>>(eob, trows, tiw, out);
}

// Round 5
// 540.862 us; speedup vs baseline: 1.1014x; 1.0270x over previous
//
#include <hip/hip_runtime.h>
#include <hip/hip_bf16.h>
#include <stdint.h>

// SparseMoE top-2/8, N=8192, D=1024, H=2048, fp32 in/out.
// R5: overlap the weight converts with useful work instead of serial prep:
//     - wgu-convert fused into router kernel (block-range split, one launch)
//     - wd-convert fused into gemm_gateup as blockIdx.z==8 slice (streams
//       under the compute-bound GEMM window, 14% HBM util has headroom)
//     - cnt zeroed via hipMemsetAsync (graph-capturable)
//     GEMM inner loop is R2's proven 2-phase dbuf + both-sides XOR swizzle
//     (648 TF; == T3-minimal recipe, at its documented 2-phase ceiling).

#define N_TOK 8192
#define D_DIM 1024
#define H_DIM 2048
#define N_EXP 8
#define N_ASSIGN (N_TOK * 2)
#define BM 128
#define BN 128
#define BK 64

typedef __attribute__((ext_vector_type(8))) short short8;   // bf16x8
typedef __attribute__((ext_vector_type(4))) float f32x4;    // MFMA acc frag

__device__ __forceinline__ unsigned short f2bf(float f) {
  union { float f; unsigned int u; } v; v.f = f;
  unsigned int r = v.u + 0x7fffu + ((v.u >> 16) & 1u);  // RTNE
  return (unsigned short)(r >> 16);
}
__device__ __forceinline__ float bf2f(unsigned short u) {
  union { float f; unsigned int u; } v; v.u = ((unsigned int)u) << 16; return v.f;
}
__device__ __forceinline__ short8 pack8(float4 a, float4 b) {
  short8 o;
  o[0] = (short)f2bf(a.x); o[1] = (short)f2bf(a.y);
  o[2] = (short)f2bf(a.z); o[3] = (short)f2bf(a.w);
  o[4] = (short)f2bf(b.x); o[5] = (short)f2bf(b.y);
  o[6] = (short)f2bf(b.z); o[7] = (short)f2bf(b.w);
  return o;
}
__device__ __forceinline__ void gload_lds16(const void* g, void* l) {
  __builtin_amdgcn_global_load_lds((const __attribute__((address_space(1))) void*)g,
                                   (__attribute__((address_space(3))) void*)l, 16, 0, 0);
}

// ---------- K1: router (blocks [0,2048)) + wgu convert (blocks [2048,18432))
__global__ __launch_bounds__(256) void router_prep_kernel(
    const float* __restrict__ x, const float* __restrict__ rw,
    const float* __restrict__ rb,
    const float* __restrict__ wg, const float* __restrict__ wu,
    unsigned short* __restrict__ xb, unsigned short* __restrict__ wgu,
    int4* __restrict__ tiidx, float2* __restrict__ tiw, int* __restrict__ cnt) {
  int b = blockIdx.x;
  int tid = threadIdx.x;
  if (b >= 2048) {
    // wgu convert: interleave gate/up at 16-row granularity -> [E][4096][D]
    int idx = b - 2048;                      // 0..16383
    int up = idx >> 13;                      // 0 = gate, 1 = up
    size_t i = (((size_t)(idx & 8191)) * 256 + tid) * 8;
    const float* src = up ? wu : wg;
    float4 a = *(const float4*)(src + i);
    float4 c = *(const float4*)(src + i + 4);
    int j = (int)(i >> 10);                  // source row = e*H + jj
    int e = j >> 11;
    int jj = j & (H_DIM - 1);
    int n = ((jj >> 4) << 5) + (up ? 16 : 0) + (jj & 15);
    size_t di = (((size_t)(e << 12) + n) << 10) + (i & 1023);
    *(short8*)(wgu + di) = pack8(a, c);
    return;
  }

  __shared__ float sw[N_EXP][D_DIM];          // 32 KB router weights
  for (int i = tid * 4; i < N_EXP * D_DIM; i += 1024)
    *(float4*)&sw[0][i] = *(const float4*)(rw + i);
  __syncthreads();

  int wave = tid >> 6, lane = tid & 63;
  int t = b * 4 + wave;
  const float2* xr = (const float2*)(x + (size_t)t * D_DIM);
  float2 xs[8];
#pragma unroll
  for (int j = 0; j < 8; j++) xs[j] = xr[lane + 64 * j];
  unsigned int* xbo = (unsigned int*)(xb + (size_t)t * D_DIM);
#pragma unroll
  for (int j = 0; j < 8; j++) {
    unsigned int pk = ((unsigned int)f2bf(xs[j].y) << 16) | (unsigned int)f2bf(xs[j].x);
    xbo[lane + 64 * j] = pk;
  }

  float logit[N_EXP];
#pragma unroll
  for (int e = 0; e < N_EXP; e++) {
    float acc = 0.f;
    const float2* swe = (const float2*)sw[e];
#pragma unroll
    for (int j = 0; j < 8; j++) {
      float2 w2 = swe[lane + 64 * j];
      acc += xs[j].x * w2.x + xs[j].y * w2.y;
    }
#pragma unroll
    for (int off = 32; off; off >>= 1) acc += __shfl_xor(acc, off);
    logit[e] = acc + rb[e];
  }
  if (lane == 0) {
    float m = logit[0];
#pragma unroll
    for (int e = 1; e < N_EXP; e++) m = fmaxf(m, logit[e]);
    float p[N_EXP], S = 0.f;
#pragma unroll
    for (int e = 0; e < N_EXP; e++) { p[e] = expf(logit[e] - m); S += p[e]; }
#pragma unroll
    for (int e = 0; e < N_EXP; e++) p[e] /= S;
    int i1 = 0; float v1 = p[0];
#pragma unroll
    for (int e = 1; e < N_EXP; e++) if (p[e] > v1) { v1 = p[e]; i1 = e; }
    int i2 = -1; float v2 = -1.f;
#pragma unroll
    for (int e = 0; e < N_EXP; e++) if (e != i1 && p[e] > v2) { v2 = p[e]; i2 = e; }
    float inv = 1.f / (v1 + v2 + 1e-9f);
    int s1 = atomicAdd(&cnt[i1], 1);
    int s2 = atomicAdd(&cnt[i2], 1);
    tiidx[t] = make_int4(i1, i2, s1, s2);
    tiw[t] = make_float2(v1 * inv, v2 * inv);
  }
}

// ---------- K2: plan = offsets + scatter, one block --------------------------
__global__ __launch_bounds__(256) void plan_kernel(
    const int4* __restrict__ tiidx, const int* __restrict__ cnt,
    int* __restrict__ off, int* __restrict__ assign, int2* __restrict__ trows) {
  __shared__ int soff[N_EXP];
  if (threadIdx.x == 0) {
    int a = 0;
    for (int e = 0; e < N_EXP; e++) { soff[e] = a; off[e] = a; a += cnt[e]; }
    off[N_EXP] = a;
  }
  __syncthreads();
  for (int t = threadIdx.x; t < N_TOK; t += 256) {
    int4 ti = tiidx[t];
    int r1 = soff[ti.x] + ti.z;
    int r2 = soff[ti.y] + ti.w;
    assign[r1] = t;
    assign[r2] = t;
    trows[t] = make_int2(r1, r2);
  }
}

// ---------- K3: GEMM1 (z<8) fused gate+up  |  wd convert (z==8) --------------
__global__ __launch_bounds__(256) void gemm_gateup(
    const unsigned short* __restrict__ xb,    // [N_TOK, D] bf16
    const unsigned short* __restrict__ wgu,   // [E*4096, D] bf16 interleaved
    const float* __restrict__ wd,             // [E*D, H] fp32 (for convert slice)
    unsigned short* __restrict__ wdb,         // [E*D, H] bf16 out
    const int* __restrict__ cnt, const int* __restrict__ off,
    const int* __restrict__ assign,
    unsigned short* __restrict__ hbuf) {      // [N_ASSIGN, H] bf16
  int tid = threadIdx.x;
  if (blockIdx.z == 8) {
    // wd fp32 -> bf16: 2048 blocks x 256 threads x 32 floats
    size_t b0 = ((size_t)(blockIdx.x + 32 * blockIdx.y)) * 8192;
#pragma unroll
    for (int it = 0; it < 4; it++) {
      size_t i = b0 + ((size_t)it * 256 + tid) * 8;
      float4 a = *(const float4*)(wd + i);
      float4 c = *(const float4*)(wd + i + 4);
      *(short8*)(wdb + i) = pack8(a, c);
    }
    return;
  }
  int e = blockIdx.z;
  int nrows = cnt[e];
  int row0 = blockIdx.y * BM;
  if (row0 >= nrows) return;
  int col0 = blockIdx.x * BN;                 // in [0, 4096)
  int base = off[e];

  __shared__ unsigned short sA[2][BM][BK];
  __shared__ unsigned short sB[2][BN][BK];

  int srow = tid >> 3;                        // 0..31
  int dst8 = (tid & 7) * 8;                   // linear LDS chunk
  int src8 = ((tid & 7) ^ (srow & 7)) * 8;    // pre-swizzled global column

  const unsigned short* asrc[4];
  const unsigned short* bsrc[4];
#pragma unroll
  for (int i = 0; i < 4; i++) {
    int r = row0 + srow + 32 * i;
    int tok = (r < nrows) ? assign[base + r] : assign[base];
    asrc[i] = xb + (size_t)tok * D_DIM + src8;
    int wrow = (e << 12) + col0 + srow + 32 * i;
    bsrc[i] = wgu + (size_t)wrow * D_DIM + src8;
  }

  int wr = (tid >> 7) & 1, wc = (tid >> 6) & 1;
  int lane = tid & 63;
  int fr = lane & 15;
  int fk = (lane >> 4) * 8;
  int rx = (fr & 7) * 8;                      // read-side swizzle XOR

  f32x4 acc[4][4];
#pragma unroll
  for (int a = 0; a < 4; a++)
#pragma unroll
    for (int b = 0; b < 4; b++) acc[a][b] = (f32x4){0.f, 0.f, 0.f, 0.f};

#define STAGE(bf, k0)                                                       \
  _Pragma("unroll")                                                         \
  for (int i = 0; i < 4; i++) {                                             \
    gload_lds16(asrc[i] + (k0), &sA[bf][srow + 32 * i][dst8]);              \
    gload_lds16(bsrc[i] + (k0), &sB[bf][srow + 32 * i][dst8]);              \
  }
#define COMPUTE(bf)                                                         \
  _Pragma("unroll")                                                         \
  for (int ks = 0; ks < 2; ks++) {                                          \
    short8 af[4], bq[4];                                                    \
    int c = (ks * 32 + fk) ^ rx;                                            \
    _Pragma("unroll")                                                       \
    for (int mb = 0; mb < 4; mb++)                                          \
      af[mb] = *(const short8*)&sA[bf][wr * 64 + mb * 16 + fr][c];          \
    _Pragma("unroll")                                                       \
    for (int nb = 0; nb < 4; nb++)                                          \
      bq[nb] = *(const short8*)&sB[bf][wc * 64 + nb * 16 + fr][c];          \
    _Pragma("unroll")                                                       \
    for (int mb = 0; mb < 4; mb++)                                          \
      _Pragma("unroll")                                                     \
      for (int nb = 0; nb < 4; nb++)                                        \
        acc[mb][nb] = __builtin_amdgcn_mfma_f32_16x16x32_bf16(              \
            af[mb], bq[nb], acc[mb][nb], 0, 0, 0);                          \
  }

  STAGE(0, 0);
  __syncthreads();
  for (int k0 = 0; k0 < D_DIM - 128; k0 += 128) {
    STAGE(1, k0 + 64);  COMPUTE(0); __syncthreads();
    STAGE(0, k0 + 128); COMPUTE(1); __syncthreads();
  }
  STAGE(1, D_DIM - 64); COMPUTE(0); __syncthreads();
  COMPUTE(1);
#undef STAGE
#undef COMPUTE

  int rowlim = nrows - row0;
#pragma unroll
  for (int mb = 0; mb < 4; mb++)
#pragma unroll
    for (int r = 0; r < 4; r++) {
      int lrow = wr * 64 + mb * 16 + (lane >> 4) * 4 + r;
      if (lrow < rowlim) {
        size_t hrow = (size_t)(base + row0 + lrow);
#pragma unroll
        for (int nbp = 0; nbp < 2; nbp++) {
          float g = acc[mb][2 * nbp][r], u = acc[mb][2 * nbp + 1][r];
          float hv = g / (1.f + __expf(-g)) * u;     // silu(g)*u
          int hcol = (col0 >> 1) + wc * 32 + nbp * 16 + (lane & 15);
          hbuf[hrow * H_DIM + hcol] = f2bf(hv);
        }
      }
    }
}

// ---------- K4: GEMM2 e_out = h @ Wd^T ---------------------------------------
__global__ __launch_bounds__(256) void gemm_down(
    const unsigned short* __restrict__ hbuf,  // [N_ASSIGN, H] bf16
    const unsigned short* __restrict__ wd,    // [E*D, H] bf16
    const int* __restrict__ cnt, const int* __restrict__ off,
    unsigned short* __restrict__ eo) {        // [N_ASSIGN, D] bf16
  int e = blockIdx.z;
  int nrows = cnt[e];
  int row0 = blockIdx.y * BM;
  if (row0 >= nrows) return;
  int col0 = blockIdx.x * BN;
  int base = off[e];

  __shared__ unsigned short sA[2][BM][BK];
  __shared__ unsigned short sB[2][BN][BK];

  int tid = threadIdx.x;
  int srow = tid >> 3;
  int dst8 = (tid & 7) * 8;
  int src8 = ((tid & 7) ^ (srow & 7)) * 8;

  const unsigned short* asrc[4];
  const unsigned short* bsrc[4];
#pragma unroll
  for (int i = 0; i < 4; i++) {
    int r = row0 + srow + 32 * i;
    int hrow = base + ((r < nrows) ? r : 0);
    asrc[i] = hbuf + (size_t)hrow * H_DIM + src8;
    int wrow = e * D_DIM + col0 + srow + 32 * i;
    bsrc[i] = wd + (size_t)wrow * H_DIM + src8;
  }

  int wr = (tid >> 7) & 1, wc = (tid >> 6) & 1;
  int lane = tid & 63;
  int fr = lane & 15;
  int fk = (lane >> 4) * 8;
  int rx = (fr & 7) * 8;

  f32x4 acc[4][4];
#pragma unroll
  for (int a = 0; a < 4; a++)
#pragma unroll
    for (int b = 0; b < 4; b++) acc[a][b] = (f32x4){0.f, 0.f, 0.f, 0.f};

#define STAGE(bf, k0)                                                       \
  _Pragma("unroll")                                                         \
  for (int i = 0; i < 4; i++) {                                             \
    gload_lds16(asrc[i] + (k0), &sA[bf][srow + 32 * i][dst8]);              \
    gload_lds16(bsrc[i] + (k0), &sB[bf][srow + 32 * i][dst8]);              \
  }
#define COMPUTE(bf)                                                         \
  _Pragma("unroll")                                                         \
  for (int ks = 0; ks < 2; ks++) {                                          \
    short8 af[4], bq[4];                                                    \
    int c = (ks * 32 + fk) ^ rx;                                            \
    _Pragma("unroll")                                                       \
    for (int mb = 0; mb < 4; mb++)                                          \
      af[mb] = *(const short8*)&sA[bf][wr * 64 + mb * 16 + fr][c];          \
    _Pragma("unroll")                                                       \
    for (int nb = 0; nb < 4; nb++)                                          \
      bq[nb] = *(const short8*)&sB[bf][wc * 64 + nb * 16 + fr][c];          \
    _Pragma("unroll")                                                       \
    for (int mb = 0; mb < 4; mb++)                                          \
      _Pragma("unroll")                                                     \
      for (int nb = 0; nb < 4; nb++)                                        \
        acc[mb][nb] = __builtin_amdgcn_mfma_f32_16x16x32_bf16(              \
            af[mb], bq[nb], acc[mb][nb], 0, 0, 0);                          \
  }

  STAGE(0, 0);
  __syncthreads();
  for (int k0 = 0; k0 < H_DIM - 128; k0 += 128) {
    STAGE(1, k0 + 64);  COMPUTE(0); __syncthreads();
    STAGE(0, k0 + 128); COMPUTE(1); __syncthreads();
  }
  STAGE(1, H_DIM - 64); COMPUTE(0); __syncthreads();
  COMPUTE(1);
#undef STAGE
#undef COMPUTE

  int rowlim = nrows - row0;
#pragma unroll
  for (int mb = 0; mb < 4; mb++)
#pragma unroll
    for (int r = 0; r < 4; r++) {
      int lrow = wr * 64 + mb * 16 + (lane >> 4) * 4 + r;
      if (lrow < rowlim) {
        size_t orow = (size_t)(base + row0 + lrow);
#pragma unroll
        for (int nb = 0; nb < 4; nb++)
          eo[orow * D_DIM + col0 + wc * 64 + nb * 16 + (lane & 15)] = f2bf(acc[mb][nb][r]);
      }
    }
}

// ---------- K5: combine out[t] = w1*eo[r1] + w2*eo[r2] -----------------------
__global__ __launch_bounds__(256) void combine_kernel(
    const unsigned short* __restrict__ eo, const int2* __restrict__ trows,
    const float2* __restrict__ tiw, float* __restrict__ out) {
  int t = blockIdx.x * 2 + (threadIdx.x >> 7);
  int l = threadIdx.x & 127;
  int c = l * 8;
  int2 r = trows[t];
  float2 w = tiw[t];
  short8 a = *(const short8*)&eo[(size_t)r.x * D_DIM + c];
  short8 b = *(const short8*)&eo[(size_t)r.y * D_DIM + c];
  float4 o0, o1;
  o0.x = w.x * bf2f((unsigned short)a[0]) + w.y * bf2f((unsigned short)b[0]);
  o0.y = w.x * bf2f((unsigned short)a[1]) + w.y * bf2f((unsigned short)b[1]);
  o0.z = w.x * bf2f((unsigned short)a[2]) + w.y * bf2f((unsigned short)b[2]);
  o0.w = w.x * bf2f((unsigned short)a[3]) + w.y * bf2f((unsigned short)b[3]);
  o1.x = w.x * bf2f((unsigned short)a[4]) + w.y * bf2f((unsigned short)b[4]);
  o1.y = w.x * bf2f((unsigned short)a[5]) + w.y * bf2f((unsigned short)b[5]);
  o1.z = w.x * bf2f((unsigned short)a[6]) + w.y * bf2f((unsigned short)b[6]);
  o1.w = w.x * bf2f((unsigned short)a[7]) + w.y * bf2f((unsigned short)b[7]);
  *(float4*)&out[(size_t)t * D_DIM + c] = o0;
  *(float4*)&out[(size_t)t * D_DIM + c + 4] = o1;
}

extern "C" void kernel_launch(void* const* d_in, const int* in_sizes, int n_in,
                              void* d_out, int out_size, void* d_ws, size_t ws_size,
                              hipStream_t stream) {
  const float* x  = (const float*)d_in[0];
  const float* rw = (const float*)d_in[1];
  const float* rb = (const float*)d_in[2];
  const float* wg = (const float*)d_in[3];
  const float* wu = (const float*)d_in[4];
  const float* wd = (const float*)d_in[5];
  float* out = (float*)d_out;

  char* ws = (char*)d_ws;
  size_t o = 0;
  auto alloc = [&](size_t b) { char* p = ws + o; o += (b + 255) & ~(size_t)255; return p; };
  unsigned short* xb  = (unsigned short*)alloc((size_t)N_TOK * D_DIM * 2);           // 16.8 MB
  unsigned short* wgu = (unsigned short*)alloc((size_t)N_EXP * 4096 * D_DIM * 2);    // 67.1 MB
  unsigned short* wdb = (unsigned short*)alloc((size_t)N_EXP * D_DIM * H_DIM * 2);   // 33.6 MB
  unsigned short* hb  = (unsigned short*)alloc((size_t)N_ASSIGN * H_DIM * 2);        // 67.1 MB
  unsigned short* eob = (unsigned short*)alloc((size_t)N_ASSIGN * D_DIM * 2);        // 33.6 MB
  int*    assign = (int*)alloc(N_ASSIGN * 4);
  int4*   tiidx  = (int4*)alloc(N_TOK * 16);
  float2* tiw    = (float2*)alloc(N_TOK * 8);
  int2*   trows  = (int2*)alloc(N_TOK * 8);
  int*    cnt    = (int*)alloc(64);
  int*    off    = (int*)alloc(64);

  hipMemsetAsync(cnt, 0, 64, stream);
  router_prep_kernel<<<2048 + 16384, 256, 0, stream>>>(
      x, rw, rb, wg, wu, xb, wgu, tiidx, tiw, cnt);
  plan_kernel<<<1, 256, 0, stream>>>(tiidx, cnt, off, assign, trows);
  gemm_gateup<<<dim3(4096 / BN, N_TOK / BM, N_EXP + 1), 256, 0, stream>>>(
      xb, wgu, wd, wdb, cnt, off, assign, hb);
  gemm_down<<<dim3(D_DIM / BN, N_TOK / BM, N_EXP), 256, 0, stream>>>(
      hb, wdb, cnt, off, eob);
  combine_kernel<<<N_TOK / 2, 256, 0, stream>>>(eob, trows, tiw, out);
}

// Round 6
// 350.310 us; speedup vs baseline: 1.7005x; 1.5440x over previous
//
#include <hip/hip_runtime.h>
#include <hip/hip_bf16.h>
#include <stdint.h>

// SparseMoE top-2/8, N=8192, D=1024, H=2048, fp32 in/out.
// R6: REMOVE ALL GLOBAL ATOMICS. R5 showed router_prep at 251us / 677 GB/s /
//     4.9% VALU -- serialized by 16K same-cacheline atomicAdds (cnt[8]).
//     Router now writes only per-token (e1,e2); a single-block plan_kernel
//     does histogram + 256-wide LDS scan + slot assignment deterministically.
//     GEMMs unchanged: 2-phase dbuf + both-sides XOR swizzle (648 TF), wd
//     convert fused as gateup z==8 slice.

#define N_TOK 8192
#define D_DIM 1024
#define H_DIM 2048
#define N_EXP 8
#define N_ASSIGN (N_TOK * 2)
#define BM 128
#define BN 128
#define BK 64

typedef __attribute__((ext_vector_type(8))) short short8;   // bf16x8
typedef __attribute__((ext_vector_type(4))) float f32x4;    // MFMA acc frag

__device__ __forceinline__ unsigned short f2bf(float f) {
  union { float f; unsigned int u; } v; v.f = f;
  unsigned int r = v.u + 0x7fffu + ((v.u >> 16) & 1u);  // RTNE
  return (unsigned short)(r >> 16);
}
__device__ __forceinline__ float bf2f(unsigned short u) {
  union { float f; unsigned int u; } v; v.u = ((unsigned int)u) << 16; return v.f;
}
__device__ __forceinline__ short8 pack8(float4 a, float4 b) {
  short8 o;
  o[0] = (short)f2bf(a.x); o[1] = (short)f2bf(a.y);
  o[2] = (short)f2bf(a.z); o[3] = (short)f2bf(a.w);
  o[4] = (short)f2bf(b.x); o[5] = (short)f2bf(b.y);
  o[6] = (short)f2bf(b.z); o[7] = (short)f2bf(b.w);
  return o;
}
__device__ __forceinline__ void gload_lds16(const void* g, void* l) {
  __builtin_amdgcn_global_load_lds((const __attribute__((address_space(1))) void*)g,
                                   (__attribute__((address_space(3))) void*)l, 16, 0, 0);
}

// ---------- K1: router (blocks [0,2048)) + wgu convert (blocks [2048,18432))
// NO atomics: emits (e1,e2) + normalized weights per token only.
__global__ __launch_bounds__(256) void router_prep_kernel(
    const float* __restrict__ x, const float* __restrict__ rw,
    const float* __restrict__ rb,
    const float* __restrict__ wg, const float* __restrict__ wu,
    unsigned short* __restrict__ xb, unsigned short* __restrict__ wgu,
    int2* __restrict__ tiidx, float2* __restrict__ tiw) {
  int b = blockIdx.x;
  int tid = threadIdx.x;
  if (b >= 2048) {
    // wgu convert: interleave gate/up at 16-row granularity -> [E][4096][D]
    int idx = b - 2048;                      // 0..16383
    int up = idx >> 13;                      // 0 = gate, 1 = up
    size_t i = (((size_t)(idx & 8191)) * 256 + tid) * 8;
    const float* src = up ? wu : wg;
    float4 a = *(const float4*)(src + i);
    float4 c = *(const float4*)(src + i + 4);
    int j = (int)(i >> 10);                  // source row = e*H + jj
    int e = j >> 11;
    int jj = j & (H_DIM - 1);
    int n = ((jj >> 4) << 5) + (up ? 16 : 0) + (jj & 15);
    size_t di = (((size_t)(e << 12) + n) << 10) + (i & 1023);
    *(short8*)(wgu + di) = pack8(a, c);
    return;
  }

  __shared__ float sw[N_EXP][D_DIM];          // 32 KB router weights
  for (int i = tid * 4; i < N_EXP * D_DIM; i += 1024)
    *(float4*)&sw[0][i] = *(const float4*)(rw + i);
  __syncthreads();

  int wave = tid >> 6, lane = tid & 63;
  int t = b * 4 + wave;
  const float2* xr = (const float2*)(x + (size_t)t * D_DIM);
  float2 xs[8];
#pragma unroll
  for (int j = 0; j < 8; j++) xs[j] = xr[lane + 64 * j];
  unsigned int* xbo = (unsigned int*)(xb + (size_t)t * D_DIM);
#pragma unroll
  for (int j = 0; j < 8; j++) {
    unsigned int pk = ((unsigned int)f2bf(xs[j].y) << 16) | (unsigned int)f2bf(xs[j].x);
    xbo[lane + 64 * j] = pk;
  }

  float logit[N_EXP];
#pragma unroll
  for (int e = 0; e < N_EXP; e++) {
    float acc = 0.f;
    const float2* swe = (const float2*)sw[e];
#pragma unroll
    for (int j = 0; j < 8; j++) {
      float2 w2 = swe[lane + 64 * j];
      acc += xs[j].x * w2.x + xs[j].y * w2.y;
    }
#pragma unroll
    for (int off = 32; off; off >>= 1) acc += __shfl_xor(acc, off);
    logit[e] = acc + rb[e];
  }
  if (lane == 0) {
    float m = logit[0];
#pragma unroll
    for (int e = 1; e < N_EXP; e++) m = fmaxf(m, logit[e]);
    float p[N_EXP], S = 0.f;
#pragma unroll
    for (int e = 0; e < N_EXP; e++) { p[e] = expf(logit[e] - m); S += p[e]; }
#pragma unroll
    for (int e = 0; e < N_EXP; e++) p[e] /= S;
    int i1 = 0; float v1 = p[0];
#pragma unroll
    for (int e = 1; e < N_EXP; e++) if (p[e] > v1) { v1 = p[e]; i1 = e; }
    int i2 = -1; float v2 = -1.f;
#pragma unroll
    for (int e = 0; e < N_EXP; e++) if (e != i1 && p[e] > v2) { v2 = p[e]; i2 = e; }
    float inv = 1.f / (v1 + v2 + 1e-9f);
    tiidx[t] = make_int2(i1, i2);
    tiw[t] = make_float2(v1 * inv, v2 * inv);
  }
}

// ---------- K2: plan = histogram + scan + slot assignment, one block, 0 atomics
__global__ __launch_bounds__(256) void plan_kernel(
    const int2* __restrict__ tiidx, int* __restrict__ cnt,
    int* __restrict__ off, int* __restrict__ assign, int2* __restrict__ trows) {
  __shared__ int sh[256][N_EXP + 1];          // +1 pad: bank-conflict-free rows
  __shared__ int soff[N_EXP];
  int tid = threadIdx.x;
  int t0 = tid * 32;                          // 32 consecutive tokens per thread

  // pass 1: per-thread histogram (own LDS row only)
#pragma unroll
  for (int e = 0; e < N_EXP; e++) sh[tid][e] = 0;
  for (int i = 0; i < 32; i++) {
    int2 te = tiidx[t0 + i];
    sh[tid][te.x]++;
    sh[tid][te.y]++;
  }
  int oc[N_EXP];
#pragma unroll
  for (int e = 0; e < N_EXP; e++) oc[e] = sh[tid][e];
  __syncthreads();

  // Hillis-Steele inclusive scan over 256 threads, all 8 experts in parallel
  for (int s = 1; s < 256; s <<= 1) {
    int v[N_EXP];
#pragma unroll
    for (int e = 0; e < N_EXP; e++) v[e] = (tid >= s) ? sh[tid - s][e] : 0;
    __syncthreads();
#pragma unroll
    for (int e = 0; e < N_EXP; e++) sh[tid][e] += v[e];
    __syncthreads();
  }

  // exclusive prefix for this thread (registers; sh still inclusive)
  int ex[N_EXP];
#pragma unroll
  for (int e = 0; e < N_EXP; e++) ex[e] = sh[tid][e] - oc[e];
  if (tid == 0) {
    int a = 0;
    for (int e = 0; e < N_EXP; e++) {
      int tot = sh[255][e];
      soff[e] = a; off[e] = a; cnt[e] = tot; a += tot;
    }
    off[N_EXP] = a;
  }
  __syncthreads();
#pragma unroll
  for (int e = 0; e < N_EXP; e++) sh[tid][e] = ex[e];  // running counters
  __syncthreads();

  // pass 2: assign rows in deterministic (token) order within each thread chunk
  for (int i = 0; i < 32; i++) {
    int t = t0 + i;
    int2 te = tiidx[t];
    int r1 = soff[te.x] + sh[tid][te.x]++;
    int r2 = soff[te.y] + sh[tid][te.y]++;
    assign[r1] = t;
    assign[r2] = t;
    trows[t] = make_int2(r1, r2);
  }
}

// ---------- K3: GEMM1 (z<8) fused gate+up  |  wd convert (z==8) --------------
__global__ __launch_bounds__(256) void gemm_gateup(
    const unsigned short* __restrict__ xb,    // [N_TOK, D] bf16
    const unsigned short* __restrict__ wgu,   // [E*4096, D] bf16 interleaved
    const float* __restrict__ wd,             // [E*D, H] fp32 (for convert slice)
    unsigned short* __restrict__ wdb,         // [E*D, H] bf16 out
    const int* __restrict__ cnt, const int* __restrict__ off,
    const int* __restrict__ assign,
    unsigned short* __restrict__ hbuf) {      // [N_ASSIGN, H] bf16
  int tid = threadIdx.x;
  if (blockIdx.z == 8) {
    size_t b0 = ((size_t)(blockIdx.x + 32 * blockIdx.y)) * 8192;
#pragma unroll
    for (int it = 0; it < 4; it++) {
      size_t i = b0 + ((size_t)it * 256 + tid) * 8;
      float4 a = *(const float4*)(wd + i);
      float4 c = *(const float4*)(wd + i + 4);
      *(short8*)(wdb + i) = pack8(a, c);
    }
    return;
  }
  int e = blockIdx.z;
  int nrows = cnt[e];
  int row0 = blockIdx.y * BM;
  if (row0 >= nrows) return;
  int col0 = blockIdx.x * BN;                 // in [0, 4096)
  int base = off[e];

  __shared__ unsigned short sA[2][BM][BK];
  __shared__ unsigned short sB[2][BN][BK];

  int srow = tid >> 3;                        // 0..31
  int dst8 = (tid & 7) * 8;                   // linear LDS chunk
  int src8 = ((tid & 7) ^ (srow & 7)) * 8;    // pre-swizzled global column

  const unsigned short* asrc[4];
  const unsigned short* bsrc[4];
#pragma unroll
  for (int i = 0; i < 4; i++) {
    int r = row0 + srow + 32 * i;
    int tok = (r < nrows) ? assign[base + r] : assign[base];
    asrc[i] = xb + (size_t)tok * D_DIM + src8;
    int wrow = (e << 12) + col0 + srow + 32 * i;
    bsrc[i] = wgu + (size_t)wrow * D_DIM + src8;
  }

  int wr = (tid >> 7) & 1, wc = (tid >> 6) & 1;
  int lane = tid & 63;
  int fr = lane & 15;
  int fk = (lane >> 4) * 8;
  int rx = (fr & 7) * 8;                      // read-side swizzle XOR

  f32x4 acc[4][4];
#pragma unroll
  for (int a = 0; a < 4; a++)
#pragma unroll
    for (int b = 0; b < 4; b++) acc[a][b] = (f32x4){0.f, 0.f, 0.f, 0.f};

#define STAGE(bf, k0)                                                       \
  _Pragma("unroll")                                                         \
  for (int i = 0; i < 4; i++) {                                             \
    gload_lds16(asrc[i] + (k0), &sA[bf][srow + 32 * i][dst8]);              \
    gload_lds16(bsrc[i] + (k0), &sB[bf][srow + 32 * i][dst8]);              \
  }
#define COMPUTE(bf)                                                         \
  _Pragma("unroll")                                                         \
  for (int ks = 0; ks < 2; ks++) {                                          \
    short8 af[4], bq[4];                                                    \
    int c = (ks * 32 + fk) ^ rx;                                            \
    _Pragma("unroll")                                                       \
    for (int mb = 0; mb < 4; mb++)                                          \
      af[mb] = *(const short8*)&sA[bf][wr * 64 + mb * 16 + fr][c];          \
    _Pragma("unroll")                                                       \
    for (int nb = 0; nb < 4; nb++)                                          \
      bq[nb] = *(const short8*)&sB[bf][wc * 64 + nb * 16 + fr][c];          \
    _Pragma("unroll")                                                       \
    for (int mb = 0; mb < 4; mb++)                                          \
      _Pragma("unroll")                                                     \
      for (int nb = 0; nb < 4; nb++)                                        \
        acc[mb][nb] = __builtin_amdgcn_mfma_f32_16x16x32_bf16(              \
            af[mb], bq[nb], acc[mb][nb], 0, 0, 0);                          \
  }

  STAGE(0, 0);
  __syncthreads();
  for (int k0 = 0; k0 < D_DIM - 128; k0 += 128) {
    STAGE(1, k0 + 64);  COMPUTE(0); __syncthreads();
    STAGE(0, k0 + 128); COMPUTE(1); __syncthreads();
  }
  STAGE(1, D_DIM - 64); COMPUTE(0); __syncthreads();
  COMPUTE(1);
#undef STAGE
#undef COMPUTE

  int rowlim = nrows - row0;
#pragma unroll
  for (int mb = 0; mb < 4; mb++)
#pragma unroll
    for (int r = 0; r < 4; r++) {
      int lrow = wr * 64 + mb * 16 + (lane >> 4) * 4 + r;
      if (lrow < rowlim) {
        size_t hrow = (size_t)(base + row0 + lrow);
#pragma unroll
        for (int nbp = 0; nbp < 2; nbp++) {
          float g = acc[mb][2 * nbp][r], u = acc[mb][2 * nbp + 1][r];
          float hv = g / (1.f + __expf(-g)) * u;     // silu(g)*u
          int hcol = (col0 >> 1) + wc * 32 + nbp * 16 + (lane & 15);
          hbuf[hrow * H_DIM + hcol] = f2bf(hv);
        }
      }
    }
}

// ---------- K4: GEMM2 e_out = h @ Wd^T ---------------------------------------
__global__ __launch_bounds__(256) void gemm_down(
    const unsigned short* __restrict__ hbuf,  // [N_ASSIGN, H] bf16
    const unsigned short* __restrict__ wd,    // [E*D, H] bf16
    const int* __restrict__ cnt, const int* __restrict__ off,
    unsigned short* __restrict__ eo) {        // [N_ASSIGN, D] bf16
  int e = blockIdx.z;
  int nrows = cnt[e];
  int row0 = blockIdx.y * BM;
  if (row0 >= nrows) return;
  int col0 = blockIdx.x * BN;
  int base = off[e];

  __shared__ unsigned short sA[2][BM][BK];
  __shared__ unsigned short sB[2][BN][BK];

  int tid = threadIdx.x;
  int srow = tid >> 3;
  int dst8 = (tid & 7) * 8;
  int src8 = ((tid & 7) ^ (srow & 7)) * 8;

  const unsigned short* asrc[4];
  const unsigned short* bsrc[4];
#pragma unroll
  for (int i = 0; i < 4; i++) {
    int r = row0 + srow + 32 * i;
    int hrow = base + ((r < nrows) ? r : 0);
    asrc[i] = hbuf + (size_t)hrow * H_DIM + src8;
    int wrow = e * D_DIM + col0 + srow + 32 * i;
    bsrc[i] = wd + (size_t)wrow * H_DIM + src8;
  }

  int wr = (tid >> 7) & 1, wc = (tid >> 6) & 1;
  int lane = tid & 63;
  int fr = lane & 15;
  int fk = (lane >> 4) * 8;
  int rx = (fr & 7) * 8;

  f32x4 acc[4][4];
#pragma unroll
  for (int a = 0; a < 4; a++)
#pragma unroll
    for (int b = 0; b < 4; b++) acc[a][b] = (f32x4){0.f, 0.f, 0.f, 0.f};

#define STAGE(bf, k0)                                                       \
  _Pragma("unroll")                                                         \
  for (int i = 0; i < 4; i++) {                                             \
    gload_lds16(asrc[i] + (k0), &sA[bf][srow + 32 * i][dst8]);              \
    gload_lds16(bsrc[i] + (k0), &sB[bf][srow + 32 * i][dst8]);              \
  }
#define COMPUTE(bf)                                                         \
  _Pragma("unroll")                                                         \
  for (int ks = 0; ks < 2; ks++) {                                          \
    short8 af[4], bq[4];                                                    \
    int c = (ks * 32 + fk) ^ rx;                                            \
    _Pragma("unroll")                                                       \
    for (int mb = 0; mb < 4; mb++)                                          \
      af[mb] = *(const short8*)&sA[bf][wr * 64 + mb * 16 + fr][c];          \
    _Pragma("unroll")                                                       \
    for (int nb = 0; nb < 4; nb++)                                          \
      bq[nb] = *(const short8*)&sB[bf][wc * 64 + nb * 16 + fr][c];          \
    _Pragma("unroll")                                                       \
    for (int mb = 0; mb < 4; mb++)                                          \
      _Pragma("unroll")                                                     \
      for (int nb = 0; nb < 4; nb++)                                        \
        acc[mb][nb] = __builtin_amdgcn_mfma_f32_16x16x32_bf16(              \
            af[mb], bq[nb], acc[mb][nb], 0, 0, 0);                          \
  }

  STAGE(0, 0);
  __syncthreads();
  for (int k0 = 0; k0 < H_DIM - 128; k0 += 128) {
    STAGE(1, k0 + 64);  COMPUTE(0); __syncthreads();
    STAGE(0, k0 + 128); COMPUTE(1); __syncthreads();
  }
  STAGE(1, H_DIM - 64); COMPUTE(0); __syncthreads();
  COMPUTE(1);
#undef STAGE
#undef COMPUTE

  int rowlim = nrows - row0;
#pragma unroll
  for (int mb = 0; mb < 4; mb++)
#pragma unroll
    for (int r = 0; r < 4; r++) {
      int lrow = wr * 64 + mb * 16 + (lane >> 4) * 4 + r;
      if (lrow < rowlim) {
        size_t orow = (size_t)(base + row0 + lrow);
#pragma unroll
        for (int nb = 0; nb < 4; nb++)
          eo[orow * D_DIM + col0 + wc * 64 + nb * 16 + (lane & 15)] = f2bf(acc[mb][nb][r]);
      }
    }
}

// ---------- K5: combine out[t] = w1*eo[r1] + w2*eo[r2] -----------------------
__global__ __launch_bounds__(256) void combine_kernel(
    const unsigned short* __restrict__ eo, const int2* __restrict__ trows,
    const float2* __restrict__ tiw, float* __restrict__ out) {
  int t = blockIdx.x * 2 + (threadIdx.x >> 7);
  int l = threadIdx.x & 127;
  int c = l * 8;
  int2 r = trows[t];
  float2 w = tiw[t];
  short8 a = *(const short8*)&eo[(size_t)r.x * D_DIM + c];
  short8 b = *(const short8*)&eo[(size_t)r.y * D_DIM + c];
  float4 o0, o1;
  o0.x = w.x * bf2f((unsigned short)a[0]) + w.y * bf2f((unsigned short)b[0]);
  o0.y = w.x * bf2f((unsigned short)a[1]) + w.y * bf2f((unsigned short)b[1]);
  o0.z = w.x * bf2f((unsigned short)a[2]) + w.y * bf2f((unsigned short)b[2]);
  o0.w = w.x * bf2f((unsigned short)a[3]) + w.y * bf2f((unsigned short)b[3]);
  o1.x = w.x * bf2f((unsigned short)a[4]) + w.y * bf2f((unsigned short)b[4]);
  o1.y = w.x * bf2f((unsigned short)a[5]) + w.y * bf2f((unsigned short)b[5]);
  o1.z = w.x * bf2f((unsigned short)a[6]) + w.y * bf2f((unsigned short)b[6]);
  o1.w = w.x * bf2f((unsigned short)a[7]) + w.y * bf2f((unsigned short)b[7]);
  *(float4*)&out[(size_t)t * D_DIM + c] = o0;
  *(float4*)&out[(size_t)t * D_DIM + c + 4] = o1;
}

extern "C" void kernel_launch(void* const* d_in, const int* in_sizes, int n_in,
                              void* d_out, int out_size, void* d_ws, size_t ws_size,
                              hipStream_t stream) {
  const float* x  = (const float*)d_in[0];
  const float* rw = (const float*)d_in[1];
  const float* rb = (const float*)d_in[2];
  const float* wg = (const float*)d_in[3];
  const float* wu = (const float*)d_in[4];
  const float* wd = (const float*)d_in[5];
  float* out = (float*)d_out;

  char* ws = (char*)d_ws;
  size_t o = 0;
  auto alloc = [&](size_t b) { char* p = ws + o; o += (b + 255) & ~(size_t)255; return p; };
  unsigned short* xb  = (unsigned short*)alloc((size_t)N_TOK * D_DIM * 2);           // 16.8 MB
  unsigned short* wgu = (unsigned short*)alloc((size_t)N_EXP * 4096 * D_DIM * 2);    // 67.1 MB
  unsigned short* wdb = (unsigned short*)alloc((size_t)N_EXP * D_DIM * H_DIM * 2);   // 33.6 MB
  unsigned short* hb  = (unsigned short*)alloc((size_t)N_ASSIGN * H_DIM * 2);        // 67.1 MB
  unsigned short* eob = (unsigned short*)alloc((size_t)N_ASSIGN * D_DIM * 2);        // 33.6 MB
  int*    assign = (int*)alloc(N_ASSIGN * 4);
  int2*   tiidx  = (int2*)alloc(N_TOK * 8);
  float2* tiw    = (float2*)alloc(N_TOK * 8);
  int2*   trows  = (int2*)alloc(N_TOK * 8);
  int*    cnt    = (int*)alloc(64);
  int*    off    = (int*)alloc(64);

  router_prep_kernel<<<2048 + 16384, 256, 0, stream>>>(
      x, rw, rb, wg, wu, xb, wgu, tiidx, tiw);
  plan_kernel<<<1, 256, 0, stream>>>(tiidx, cnt, off, assign, trows);
  gemm_gateup<<<dim3(4096 / BN, N_TOK / BM, N_EXP + 1), 256, 0, stream>>>(
      xb, wgu, wd, wdb, cnt, off, assign, hb);
  gemm_down<<<dim3(D_DIM / BN, N_TOK / BM, N_EXP), 256, 0, stream>>>(
      hb, wdb, cnt, off, eob);
  combine_kernel<<<N_TOK / 2, 256, 0, stream>>>(eob, trows, tiw, out);
}